// Round 7
// baseline (926.141 us; speedup 1.0000x reference)
//
#include <hip/hip_runtime.h>
#include <stdint.h>

#define NM 10000
#define NG 100000
#define NE 300000
#define DD 256
#define HH 256
#define NB ((NE + 63) / 64)   // edge tiles / blocks

typedef unsigned short u16;
typedef float f32x4 __attribute__((ext_vector_type(4)));
typedef short bf16x8 __attribute__((ext_vector_type(8)));

__device__ __forceinline__ u16 f2bf(float f) {
    union { float f; unsigned int i; } v; v.f = f;
    unsigned int x = v.i;
    x += 0x7fffu + ((x >> 16) & 1u);   // RNE
    return (u16)(x >> 16);
}
__device__ __forceinline__ unsigned int pack2(u16 lo, u16 hi) {
    return (unsigned int)lo | ((unsigned int)hi << 16);
}
__device__ __forceinline__ uint4 pack8(float4 v0, float4 v1) {
    uint4 o;
    o.x = pack2(f2bf(v0.x), f2bf(v0.y));
    o.y = pack2(f2bf(v0.z), f2bf(v0.w));
    o.z = pack2(f2bf(v1.x), f2bf(v1.y));
    o.w = pack2(f2bf(v1.z), f2bf(v1.w));
    return o;
}

// ---- fused: 4x weight transpose+downcast (blocks 0..95) + dst histogram ----
__global__ void transpose_hist(const float* __restrict__ w1e, const float* __restrict__ w2e,
                               const float* __restrict__ w1g, const float* __restrict__ w2g,
                               u16* __restrict__ o1e, u16* __restrict__ o2e,
                               u16* __restrict__ o1g, u16* __restrict__ o2g,
                               const int* __restrict__ edst, int* __restrict__ cnt) {
    __shared__ float tile[64][68];        // +4 pad, rows 16B aligned
    const int b = blockIdx.x;
    const int tid = threadIdx.x;
    if (b >= 96) {                        // histogram part (256 blocks)
        int i = (b - 96) * 256 + tid;
        for (; i < NE; i += 256 * 256) atomicAdd(&cnt[edst[i]], 1);
        return;
    }
    const float* in; u16* out; int K, tb;
    if (b < 32)      { in = w1e; out = o1e; K = 512; tb = b; }
    else if (b < 48) { in = w2e; out = o2e; K = 256; tb = b - 32; }
    else if (b < 80) { in = w1g; out = o1g; K = 512; tb = b - 48; }
    else             { in = w2g; out = o2g; K = 256; tb = b - 80; }
    const int N = 256;
    const int ntn = N >> 6;               // 4
    const int tk = tb / ntn, tn = tb % ntn;
    const int k0 = tk << 6, n0 = tn << 6;
    #pragma unroll
    for (int i = 0; i < 4; ++i) {
        int flat = tid + 256 * i;
        int r = flat >> 4;
        int c = (flat & 15) << 2;
        *(float4*)&tile[r][c] = *(const float4*)(in + (size_t)(k0 + r) * N + n0 + c);
    }
    __syncthreads();
    #pragma unroll
    for (int i = 0; i < 2; ++i) {
        int flat = tid + 256 * i;
        int r = flat >> 3;
        int c = (flat & 7) << 3;
        uint4 o;
        o.x = pack2(f2bf(tile[c + 0][r]), f2bf(tile[c + 1][r]));
        o.y = pack2(f2bf(tile[c + 2][r]), f2bf(tile[c + 3][r]));
        o.z = pack2(f2bf(tile[c + 4][r]), f2bf(tile[c + 5][r]));
        o.w = pack2(f2bf(tile[c + 6][r]), f2bf(tile[c + 7][r]));
        *(uint4*)(out + (size_t)(n0 + r) * K + k0 + c) = o;
    }
}

// one block, 1024 threads; cnt may alias cursor (in-place read-then-write).
__global__ void scan_k(const int* cnt, int* row_start, int* cursor) {
    __shared__ int part[1024];
    const int t = threadIdx.x;
    const int chunk = (NG + 1023) / 1024;       // 98
    const int lo = t * chunk;
    const int hi = (lo + chunk < NG) ? lo + chunk : NG;
    int s = 0;
    for (int i = lo; i < hi; ++i) s += cnt[i];
    const int own = s;
    part[t] = s;
    __syncthreads();
    for (int off = 1; off < 1024; off <<= 1) {
        int v = (t >= off) ? part[t - off] : 0;
        __syncthreads();
        part[t] += v;
        __syncthreads();
    }
    int run = part[t] - own;                    // exclusive prefix
    for (int i = lo; i < hi; ++i) {
        int v = cnt[i];
        row_start[i] = run;
        cursor[i] = run;
        run += v;
    }
    if (t == 0) row_start[NG] = NE;
}

__global__ void scatter_k(const int* __restrict__ edst, int* cursor,
                          int* __restrict__ eid) {
    int i = blockIdx.x * blockDim.x + threadIdx.x;
    const int stride = gridDim.x * blockDim.x;
    for (; i < NE; i += stride) {
        int pos = atomicAdd(&cursor[edst[i]], 1);
        eid[pos] = i;
    }
}

// ---- mesh_part = mesh_x @ w1e[:256,:]  (f32 out, no bias) ----------------
// r2-style 2-barrier tile GEMM, K=256. w1T layout [n=256][k=512]; top half
// of each row is k<256.
__global__ __launch_bounds__(256, 2) void mp_k(
    const float* __restrict__ mesh_x, const u16* __restrict__ w1T,
    float* __restrict__ mesh_part)
{
    __shared__ u16 aC[64 * 32];
    __shared__ u16 bC[256 * 32];

    const int tid = threadIdx.x;
    const int r0 = blockIdx.x * 64;
    const int wv = tid >> 6;
    const int lane = tid & 63;
    const int m = lane & 15;
    const int q = lane >> 4;
    const int sr = tid >> 2;
    const int sc8 = (tid & 3) * 8;
    int srow = r0 + sr; if (srow >= NM) srow = NM - 1;

    f32x4 zero = {0.f, 0.f, 0.f, 0.f};
    f32x4 acc[4][4];
    #pragma unroll
    for (int i = 0; i < 4; ++i)
        #pragma unroll
        for (int j = 0; j < 4; ++j) acc[i][j] = zero;

    for (int kt = 0; kt < 8; ++kt) {
        const int kg = kt * 32;
        if (kt) __syncthreads();
        {
            const float* p = mesh_x + (size_t)srow * DD + kg + sc8;
            float4 v0 = *(const float4*)p;
            float4 v1 = *(const float4*)(p + 4);
            *(uint4*)&aC[sr * 32 + sc8] = pack8(v0, v1);
        }
        #pragma unroll
        for (int i = 0; i < 4; ++i) {
            int flat = tid + 256 * i;
            int n = flat >> 2;
            int c = (flat & 3) * 8;
            *(uint4*)&bC[n * 32 + c] = *(const uint4*)(w1T + (size_t)n * 512 + kg + c);
        }
        __syncthreads();
        bf16x8 af[4], bfr[4];
        #pragma unroll
        for (int et = 0; et < 4; ++et)
            af[et] = *(const bf16x8*)&aC[(et * 16 + m) * 32 + q * 8];
        #pragma unroll
        for (int ht = 0; ht < 4; ++ht)
            bfr[ht] = *(const bf16x8*)&bC[(wv * 64 + ht * 16 + m) * 32 + q * 8];
        #pragma unroll
        for (int ht = 0; ht < 4; ++ht)
            #pragma unroll
            for (int et = 0; et < 4; ++et)
                acc[ht][et] = __builtin_amdgcn_mfma_f32_16x16x32_bf16(
                    bfr[ht], af[et], acc[ht][et], 0, 0, 0);
    }

    #pragma unroll
    for (int nt = 0; nt < 4; ++nt) {
        const int nb = wv * 64 + nt * 16 + q * 4;
        #pragma unroll
        for (int et = 0; et < 4; ++et) {
            const int r = r0 + et * 16 + m;
            if (r < NM) {
                float4 o;
                o.x = acc[nt][et][0];
                o.y = acc[nt][et][1];
                o.z = acc[nt][et][2];
                o.w = acc[nt][et][3];
                *(float4*)(mesh_part + (size_t)r * HH + nb) = o;
            }
        }
    }
}

// ---------------- edge MLP + GEMM3 segment-sum aggregation ----------------
// One block per 64 CSR-consecutive edges. BURST A-STAGE: the whole 64x256
// grid_x[dst] A-matrix is gathered ONCE (16 independent float4 loads per
// thread, one latency exposure) into LDS; GEMM1's 8 k-steps then read only
// LDS + L2-hot weights -> per-step exposed latency drops from ~HBM-gather
// to ~L2. A-region is reused as hL after GEMM1 (barrier-separated).
// Mesh side from precomputed mesh_part[src] (f32, L2-resident, 10 MB).
// GEMM3 one-pass hi/lo (acc dead before acc3 lives -> no spill at (256,2)).
__global__ __launch_bounds__(256, 2) void edge_mlp_csr(
    const float* __restrict__ grid_x, const float* __restrict__ mesh_part,
    const int* __restrict__ esrc, const int* __restrict__ edst,
    const int* __restrict__ eid,
    const u16* __restrict__ w1T, const float* __restrict__ b1,
    const u16* __restrict__ w2T, const float* __restrict__ b2,
    float* __restrict__ agg)
{
    extern __shared__ char smem[];
    // main phase:
    u16* bC = (u16*)smem;                 // [256][32]               16384 B
    u16* hL = bC + 256 * 32;              // A-stage then h1 [64][272] 34816 B (ends 51200)
    // GEMM3 overlays (bC/hL dead by then):
    u16* hA = (u16*)smem;                 // h2hi [256][64] swz      32768 B
    u16* sS = (u16*)(smem + 32768);       // S    [64][64]  swz       8192 B
    u16* hB = (u16*)(smem + 40960);       // h2lo [256][64] swz      32768 B (ends 73728)
    // tail (never overlaid):
    int* ssrc = (int*)(smem + 73728);     // [64]
    int* sdst = ssrc + 64;                // [64]
    int* rowOfRank = sdst + 64;           // [64]
    int* miscL = rowOfRank + 64;          // [1] nD

    const int tid = threadIdx.x;
    const int e0 = blockIdx.x * 64;
    const int nT = (NE - e0 < 64) ? (NE - e0) : 64;

    const int wv = tid >> 6;
    const int lane = tid & 63;
    const int m = lane & 15;
    const int q = lane >> 4;
    const int sr = tid >> 2;              // staging row 0..63 (edge in tile)
    const int sc8 = (tid & 3) * 8;        // staging col (8 f32 per lane)

    int eS; { int ii = e0 + sr; eS = eid[(ii < NE) ? ii : NE - 1]; }
    const int rdst = edst[eS];
    if (tid < 64) {
        int ii = e0 + tid;
        int e = eid[(ii < NE) ? ii : NE - 1];
        ssrc[tid] = esrc[e];
        sdst[tid] = edst[e];
    }

    // ---- burst gather: A = grid_x[dst] (64x256 f32) -> bf16 LDS, one shot --
    {
        float4 va[16];
        #pragma unroll
        for (int it = 0; it < 8; ++it) {
            const float* p = grid_x + (size_t)rdst * DD + it * 32 + sc8;
            va[2 * it]     = *(const float4*)p;
            va[2 * it + 1] = *(const float4*)(p + 4);
        }
        #pragma unroll
        for (int it = 0; it < 8; ++it)
            *(uint4*)&hL[sr * 272 + it * 32 + sc8] = pack8(va[2 * it], va[2 * it + 1]);
    }

    f32x4 zero = {0.f, 0.f, 0.f, 0.f};
    f32x4 acc[4][4];
    #pragma unroll
    for (int i = 0; i < 4; ++i)
        #pragma unroll
        for (int j = 0; j < 4; ++j) acc[i][j] = zero;

    __syncthreads();                      // A + indices visible

    // ---- GEMM1 (grid side): K = 256; only bC staged per step (L2-hot) ----
    for (int kt = 0; kt < 8; ++kt) {
        const int kg = kt * 32;
        if (kt) __syncthreads();
        #pragma unroll
        for (int i = 0; i < 4; ++i) {
            int flat = tid + 256 * i;
            int n = flat >> 2;
            int c = (flat & 3) * 8;
            *(uint4*)&bC[n * 32 + c] = *(const uint4*)(w1T + (size_t)n * 512 + 256 + kg + c);
        }
        __syncthreads();
        bf16x8 af[4], bfr[4];
        #pragma unroll
        for (int et = 0; et < 4; ++et)
            af[et] = *(const bf16x8*)&hL[(et * 16 + m) * 272 + kg + q * 8];
        #pragma unroll
        for (int ht = 0; ht < 4; ++ht)
            bfr[ht] = *(const bf16x8*)&bC[(wv * 64 + ht * 16 + m) * 32 + q * 8];
        #pragma unroll
        for (int ht = 0; ht < 4; ++ht)
            #pragma unroll
            for (int et = 0; et < 4; ++et)
                acc[ht][et] = __builtin_amdgcn_mfma_f32_16x16x32_bf16(
                    bfr[ht], af[et], acc[ht][et], 0, 0, 0);
    }
    __syncthreads();                      // all A reads done before h1 overwrite

    // ---- epilogue 1: h1 = relu(acc + mesh_part[src] + b1) -> hL bf16 ----
    #pragma unroll
    for (int ht = 0; ht < 4; ++ht) {
        const int hb = wv * 64 + ht * 16 + q * 4;
        const float4 bb = *(const float4*)(b1 + hb);
        #pragma unroll
        for (int et = 0; et < 4; ++et) {
            const int e = et * 16 + m;
            const float4 mp = *(const float4*)(mesh_part + (size_t)ssrc[e] * HH + hb);
            ushort4 o;
            o.x = f2bf(fmaxf(acc[ht][et][0] + mp.x + bb.x, 0.f));
            o.y = f2bf(fmaxf(acc[ht][et][1] + mp.y + bb.y, 0.f));
            o.z = f2bf(fmaxf(acc[ht][et][2] + mp.z + bb.z, 0.f));
            o.w = f2bf(fmaxf(acc[ht][et][3] + mp.w + bb.w, 0.f));
            *(ushort4*)&hL[e * 272 + hb] = o;
        }
    }
    #pragma unroll
    for (int i = 0; i < 4; ++i)
        #pragma unroll
        for (int j = 0; j < 4; ++j) acc[i][j] = zero;
    __syncthreads();                      // h1 visible

    // ---- GEMM2: K = 256 ----
    for (int kt = 0; kt < 8; ++kt) {
        const int kg = kt * 32;
        if (kt) __syncthreads();
        #pragma unroll
        for (int i = 0; i < 4; ++i) {
            int flat = tid + 256 * i;
            int n = flat >> 2;
            int c = (flat & 3) * 8;
            *(uint4*)&bC[n * 32 + c] = *(const uint4*)(w2T + (size_t)n * 256 + kg + c);
        }
        __syncthreads();
        bf16x8 af[4], bfr[4];
        #pragma unroll
        for (int et = 0; et < 4; ++et)
            af[et] = *(const bf16x8*)&hL[(et * 16 + m) * 272 + kg + q * 8];
        #pragma unroll
        for (int ht = 0; ht < 4; ++ht)
            bfr[ht] = *(const bf16x8*)&bC[(wv * 64 + ht * 16 + m) * 32 + q * 8];
        #pragma unroll
        for (int ht = 0; ht < 4; ++ht)
            #pragma unroll
            for (int et = 0; et < 4; ++et)
                acc[ht][et] = __builtin_amdgcn_mfma_f32_16x16x32_bf16(
                    bfr[ht], af[et], acc[ht][et], 0, 0, 0);
    }

    // ---- GEMM3 phase A: consume acc ONCE -> h2hi/h2lo LDS; zero S ----
    __syncthreads();                      // all GEMM2 reads of bC/hL done
    #pragma unroll
    for (int nt = 0; nt < 4; ++nt) {
        const int hb = wv * 64 + nt * 16 + q * 4;
        const float4 bb = *(const float4*)(b2 + hb);
        #pragma unroll
        for (int et = 0; et < 4; ++et) {
            const int el = et * 16 + m;
            #pragma unroll
            for (int j = 0; j < 4; ++j) {
                float x = acc[nt][et][j] +
                          ((j == 0) ? bb.x : (j == 1) ? bb.y : (j == 2) ? bb.z : bb.w);
                u16 hi = f2bf(x);
                union { unsigned int i; float f; } hf2;
                hf2.i = ((unsigned int)hi) << 16;
                u16 lo = f2bf(x - hf2.f);
                const int row = hb + j;
                const int col = (el & 7) | (((el >> 3) ^ (row & 7)) << 3);
                hA[row * 64 + col] = hi;
                hB[row * 64 + col] = lo;
            }
        }
    }
    for (int i = tid; i < (64 * 64) / 8; i += 256)
        ((uint4*)sS)[i] = make_uint4(0, 0, 0, 0);
    __syncthreads();

    // ---- rank ballot -> rowOfRank, one-hot S (swizzled) ----
    if (tid < 64) {
        int d = sdst[tid];
        bool flag = (tid > 0) && (tid < nT) && (d != sdst[tid - 1]);
        unsigned long long mask = __ballot(flag);
        int rk = (int)__popcll(mask & ((2ull << tid) - 1ull));
        if (tid < nT) {
            rowOfRank[rk] = d;
            const int scol = (tid & 7) | (((tid >> 3) ^ (rk & 7)) << 3);
            sS[rk * 64 + scol] = (u16)0x3F80;         // bf16 1.0
        }
        if (tid == 0) miscL[0] = (int)__popcll(mask) + 1;
    }
    __syncthreads();

    // ---- GEMM3 phase B: acc3 = (h2hi + h2lo) x S, 4 MFMA steps ----
    f32x4 acc3[4][4];
    #pragma unroll
    for (int i = 0; i < 4; ++i)
        #pragma unroll
        for (int j = 0; j < 4; ++j) acc3[i][j] = zero;

    #pragma unroll
    for (int ph = 0; ph < 2; ++ph) {
        const u16* hsrc = ph ? hB : hA;
        #pragma unroll
        for (int ks = 0; ks < 2; ++ks) {
            bf16x8 hf[4], sf[4];
            #pragma unroll
            for (int ht = 0; ht < 4; ++ht) {
                const int r = wv * 64 + ht * 16 + m;
                const int cs = ((ks * 4 + q) ^ (r & 7)) * 8;
                hf[ht] = *(const bf16x8*)&hsrc[r * 64 + cs];
            }
            #pragma unroll
            for (int rt = 0; rt < 4; ++rt) {
                const int rs = rt * 16 + m;
                const int cs = ((ks * 4 + q) ^ (rs & 7)) * 8;
                sf[rt] = *(const bf16x8*)&sS[rs * 64 + cs];
            }
            #pragma unroll
            for (int ht = 0; ht < 4; ++ht)
                #pragma unroll
                for (int rt = 0; rt < 4; ++rt)
                    acc3[ht][rt] = __builtin_amdgcn_mfma_f32_16x16x32_bf16(
                        hf[ht], sf[rt], acc3[ht][rt], 0, 0, 0);
        }
    }

    // ---- epilogue 3: store per-rank partial sums ----
    const int nD = miscL[0];
    #pragma unroll
    for (int ht = 0; ht < 4; ++ht) {
        const int h0 = wv * 64 + ht * 16 + q * 4;
        #pragma unroll
        for (int rt = 0; rt < 4; ++rt) {
            const int r = rt * 16 + m;
            if (r < nD) {
                float* p = agg + (size_t)rowOfRank[r] * HH + h0;
                if (r == 0 || r == nD - 1) {      // may straddle block boundary
                    unsafeAtomicAdd(p + 0, acc3[ht][rt][0]);
                    unsafeAtomicAdd(p + 1, acc3[ht][rt][1]);
                    unsafeAtomicAdd(p + 2, acc3[ht][rt][2]);
                    unsafeAtomicAdd(p + 3, acc3[ht][rt][3]);
                } else {                          // exclusively owned row
                    float4 o;
                    o.x = acc3[ht][rt][0];
                    o.y = acc3[ht][rt][1];
                    o.z = acc3[ht][rt][2];
                    o.w = acc3[ht][rt][3];
                    *(float4*)p = o;
                }
            }
        }
    }
}

// ---------------- grid MLP + residual (burst A-stage x2) ----------------
// Same burst trick: GEMM1's A (concat grid_x | agg, K=512) staged in two
// 64x256 bursts; the 16 k-steps stage only L2-hot weights. MFMA order
// identical to r6 -> bit-identical output. aC buffer deleted (LDS 51.2 KB).
// agg is f32 [NG][HH] living in d_out; block-local read-then-write.
// NOTE: agg and out alias — no __restrict__ on them.
__global__ __launch_bounds__(256, 2) void grid_mlp(
    const float* __restrict__ grid_x, const float* agg,
    const u16* __restrict__ w1T, const float* __restrict__ b1,
    const u16* __restrict__ w2T, const float* __restrict__ b2,
    float* out)
{
    __shared__ u16 bC[256 * 32];
    __shared__ u16 hL[64 * 272];          // A-stage then h1

    const int tid = threadIdx.x;
    const int r0 = blockIdx.x * 64;
    const int wv = tid >> 6;
    const int lane = tid & 63;
    const int m = lane & 15;
    const int q = lane >> 4;
    const int sr = tid >> 2;
    const int sc8 = (tid & 3) * 8;
    int srow = r0 + sr; if (srow >= NG) srow = NG - 1;  // clamp stays inside block

    f32x4 zero = {0.f, 0.f, 0.f, 0.f};
    f32x4 acc[4][4];
    #pragma unroll
    for (int i = 0; i < 4; ++i)
        #pragma unroll
        for (int j = 0; j < 4; ++j) acc[i][j] = zero;

    // ---- half 1: burst A = grid_x[srow] cols 0..255, then 8 k-steps ----
    {
        float4 va[16];
        #pragma unroll
        for (int it = 0; it < 8; ++it) {
            const float* p = grid_x + (size_t)srow * DD + it * 32 + sc8;
            va[2 * it]     = *(const float4*)p;
            va[2 * it + 1] = *(const float4*)(p + 4);
        }
        #pragma unroll
        for (int it = 0; it < 8; ++it)
            *(uint4*)&hL[sr * 272 + it * 32 + sc8] = pack8(va[2 * it], va[2 * it + 1]);
    }
    __syncthreads();
    for (int kt = 0; kt < 8; ++kt) {
        const int kg = kt * 32;
        if (kt) __syncthreads();
        #pragma unroll
        for (int i = 0; i < 4; ++i) {
            int flat = tid + 256 * i;
            int n = flat >> 2;
            int c = (flat & 3) * 8;
            *(uint4*)&bC[n * 32 + c] = *(const uint4*)(w1T + (size_t)n * 512 + kg + c);
        }
        __syncthreads();
        bf16x8 af[4], bfr[4];
        #pragma unroll
        for (int et = 0; et < 4; ++et)
            af[et] = *(const bf16x8*)&hL[(et * 16 + m) * 272 + kg + q * 8];
        #pragma unroll
        for (int ht = 0; ht < 4; ++ht)
            bfr[ht] = *(const bf16x8*)&bC[(wv * 64 + ht * 16 + m) * 32 + q * 8];
        #pragma unroll
        for (int ht = 0; ht < 4; ++ht)
            #pragma unroll
            for (int et = 0; et < 4; ++et)
                acc[ht][et] = __builtin_amdgcn_mfma_f32_16x16x32_bf16(
                    bfr[ht], af[et], acc[ht][et], 0, 0, 0);
    }
    __syncthreads();                      // A reads done before overwrite

    // ---- half 2: burst A = agg[srow] cols 0..255, then 8 k-steps ----
    {
        float4 va[16];
        #pragma unroll
        for (int it = 0; it < 8; ++it) {
            const float* p = agg + (size_t)srow * HH + it * 32 + sc8;
            va[2 * it]     = *(const float4*)p;
            va[2 * it + 1] = *(const float4*)(p + 4);
        }
        #pragma unroll
        for (int it = 0; it < 8; ++it)
            *(uint4*)&hL[sr * 272 + it * 32 + sc8] = pack8(va[2 * it], va[2 * it + 1]);
    }
    __syncthreads();
    for (int kt = 0; kt < 8; ++kt) {
        const int kg = kt * 32;
        if (kt) __syncthreads();
        #pragma unroll
        for (int i = 0; i < 4; ++i) {
            int flat = tid + 256 * i;
            int n = flat >> 2;
            int c = (flat & 3) * 8;
            *(uint4*)&bC[n * 32 + c] = *(const uint4*)(w1T + (size_t)n * 512 + 256 + kg + c);
        }
        __syncthreads();
        bf16x8 af[4], bfr[4];
        #pragma unroll
        for (int et = 0; et < 4; ++et)
            af[et] = *(const bf16x8*)&hL[(et * 16 + m) * 272 + kg + q * 8];
        #pragma unroll
        for (int ht = 0; ht < 4; ++ht)
            bfr[ht] = *(const bf16x8*)&bC[(wv * 64 + ht * 16 + m) * 32 + q * 8];
        #pragma unroll
        for (int ht = 0; ht < 4; ++ht)
            #pragma unroll
            for (int et = 0; et < 4; ++et)
                acc[ht][et] = __builtin_amdgcn_mfma_f32_16x16x32_bf16(
                    bfr[ht], af[et], acc[ht][et], 0, 0, 0);
    }
    __syncthreads();                      // A reads done before h1 overwrite

    // ---- epilogue 1: bias + relu -> hL ----
    #pragma unroll
    for (int ht = 0; ht < 4; ++ht) {
        const int hb = wv * 64 + ht * 16 + q * 4;
        const float4 bb = *(const float4*)(b1 + hb);
        #pragma unroll
        for (int et = 0; et < 4; ++et) {
            const int e = et * 16 + m;
            ushort4 o;
            o.x = f2bf(fmaxf(acc[ht][et][0] + bb.x, 0.f));
            o.y = f2bf(fmaxf(acc[ht][et][1] + bb.y, 0.f));
            o.z = f2bf(fmaxf(acc[ht][et][2] + bb.z, 0.f));
            o.w = f2bf(fmaxf(acc[ht][et][3] + bb.w, 0.f));
            *(ushort4*)&hL[e * 272 + hb] = o;
        }
    }
    #pragma unroll
    for (int i = 0; i < 4; ++i)
        #pragma unroll
        for (int j = 0; j < 4; ++j) acc[i][j] = zero;
    __syncthreads();

    // ---- GEMM2: K = 256 ----
    for (int kt = 0; kt < 8; ++kt) {
        const int kg = kt * 32;
        if (kt) __syncthreads();
        #pragma unroll
        for (int i = 0; i < 4; ++i) {
            int flat = tid + 256 * i;
            int n = flat >> 2;
            int c = (flat & 3) * 8;
            *(uint4*)&bC[n * 32 + c] = *(const uint4*)(w2T + (size_t)n * 256 + kg + c);
        }
        __syncthreads();
        bf16x8 af[4], bfr[4];
        #pragma unroll
        for (int et = 0; et < 4; ++et)
            af[et] = *(const bf16x8*)&hL[(et * 16 + m) * 272 + kg + q * 8];
        #pragma unroll
        for (int ht = 0; ht < 4; ++ht)
            bfr[ht] = *(const bf16x8*)&bC[(wv * 64 + ht * 16 + m) * 32 + q * 8];
        #pragma unroll
        for (int ht = 0; ht < 4; ++ht)
            #pragma unroll
            for (int et = 0; et < 4; ++et)
                acc[ht][et] = __builtin_amdgcn_mfma_f32_16x16x32_bf16(
                    bfr[ht], af[et], acc[ht][et], 0, 0, 0);
    }

    // ---- epilogue: + b2 + residual grid_x, store f32 (overwrites agg rows)
    #pragma unroll
    for (int nt = 0; nt < 4; ++nt) {
        const int nb = wv * 64 + nt * 16 + q * 4;
        const float4 bb = *(const float4*)(b2 + nb);
        #pragma unroll
        for (int et = 0; et < 4; ++et) {
            const int r = r0 + et * 16 + m;
            if (r < NG) {
                const float4 g = *(const float4*)(grid_x + (size_t)r * DD + nb);
                float4 o;
                o.x = acc[nt][et][0] + bb.x + g.x;
                o.y = acc[nt][et][1] + bb.y + g.y;
                o.z = acc[nt][et][2] + bb.z + g.z;
                o.w = acc[nt][et][3] + bb.w + g.w;
                *(float4*)(out + (size_t)r * DD + nb) = o;
            }
        }
    }
}

extern "C" void kernel_launch(void* const* d_in, const int* in_sizes, int n_in,
                              void* d_out, int out_size, void* d_ws, size_t ws_size,
                              hipStream_t stream)
{
    const float* mesh_x = (const float*)d_in[0];
    const float* grid_x = (const float*)d_in[1];
    const int* esrc     = (const int*)d_in[2];
    const int* edst     = (const int*)d_in[3];
    const float* w1e    = (const float*)d_in[4];
    const float* b1e    = (const float*)d_in[5];
    const float* w2e    = (const float*)d_in[6];
    const float* b2e    = (const float*)d_in[7];
    const float* w1g    = (const float*)d_in[8];
    const float* b1g    = (const float*)d_in[9];
    const float* w2g    = (const float*)d_in[10];
    const float* b2g    = (const float*)d_in[11];
    float* out = (float*)d_out;

    // d_ws layout: 4 transposed bf16 weights (768 KB) + CSR (2.0 MB)
    //              + mesh_part f32 [NM][HH] (10.24 MB)  => ~13 MB total
    u16* w1eT = (u16*)d_ws;
    u16* w2eT = w1eT + 512 * 256;
    u16* w1gT = w2eT + 256 * 256;
    u16* w2gT = w1gT + 512 * 256;
    int* row_start = (int*)(w2gT + 256 * 256);   // [NG+4] (pad keeps 16B align)
    int* cursor    = row_start + NG + 4;         // [NG]
    int* eid       = cursor + NG;                // [NE]
    float* mesh_part = (float*)(eid + NE);       // [NM][HH] f32

    // agg f32 [NG][HH] lives in d_out; zero it (atomic targets + empty rows)
    hipMemsetAsync(d_out, 0, (size_t)NG * HH * sizeof(float), stream);
    hipMemsetAsync(cursor, 0, (size_t)NG * sizeof(int), stream);

    // fused: 4 weight transposes (96 blocks) + dst histogram (256 blocks)
    transpose_hist<<<96 + 256, 256, 0, stream>>>(
        w1e, w2e, w1g, w2g, w1eT, w2eT, w1gT, w2gT, edst, cursor);

    scan_k<<<1, 1024, 0, stream>>>(cursor, row_start, cursor);
    scatter_k<<<256, 256, 0, stream>>>(edst, cursor, eid);

    // mesh_part = mesh_x @ w1e_top  (f32)
    mp_k<<<(NM + 63) / 64, 256, 0, stream>>>(mesh_x, w1eT, mesh_part);

    // edge MLP + GEMM3 aggregation (boundary-only atomics)
    const int smem_bytes = 73728 + 784;   // 74512 B -> 2 blocks/CU
    hipFuncSetAttribute(reinterpret_cast<const void*>(edge_mlp_csr),
                        hipFuncAttributeMaxDynamicSharedMemorySize, smem_bytes);
    edge_mlp_csr<<<NB, 256, smem_bytes, stream>>>(
        grid_x, mesh_part, esrc, edst, eid,
        w1eT, b1e, w2eT, b2e, (float*)d_out);

    grid_mlp<<<(NG + 63) / 64, 256, 0, stream>>>(
        grid_x, (const float*)d_out, w1gT, b1g, w2gT, b2g, out);
}

// Round 9
// 854.720 us; speedup vs baseline: 1.0836x; 1.0836x over previous
//
#include <hip/hip_runtime.h>
#include <stdint.h>

#define NM 10000
#define NG 100000
#define NE 300000
#define DD 256
#define HH 256
#define NB ((NE + 63) / 64)   // edge tiles / blocks

typedef unsigned short u16;
typedef float f32x4 __attribute__((ext_vector_type(4)));
typedef short bf16x8 __attribute__((ext_vector_type(8)));

__device__ __forceinline__ u16 f2bf(float f) {
    union { float f; unsigned int i; } v; v.f = f;
    unsigned int x = v.i;
    x += 0x7fffu + ((x >> 16) & 1u);   // RNE
    return (u16)(x >> 16);
}
__device__ __forceinline__ unsigned int pack2(u16 lo, u16 hi) {
    return (unsigned int)lo | ((unsigned int)hi << 16);
}
__device__ __forceinline__ uint4 pack8(float4 v0, float4 v1) {
    uint4 o;
    o.x = pack2(f2bf(v0.x), f2bf(v0.y));
    o.y = pack2(f2bf(v0.z), f2bf(v0.w));
    o.z = pack2(f2bf(v1.x), f2bf(v1.y));
    o.w = pack2(f2bf(v1.z), f2bf(v1.w));
    return o;
}

// ---- fused: 4x weight transpose+downcast (blocks 0..95) + dst histogram ----
__global__ void transpose_hist(const float* __restrict__ w1e, const float* __restrict__ w2e,
                               const float* __restrict__ w1g, const float* __restrict__ w2g,
                               u16* __restrict__ o1e, u16* __restrict__ o2e,
                               u16* __restrict__ o1g, u16* __restrict__ o2g,
                               const int* __restrict__ edst, int* __restrict__ cnt) {
    __shared__ float tile[64][68];        // +4 pad, rows 272 B (16B-aligned)
    const int b = blockIdx.x;
    const int tid = threadIdx.x;
    if (b >= 96) {                        // histogram part (256 blocks)
        int i = (b - 96) * 256 + tid;
        for (; i < NE; i += 256 * 256) atomicAdd(&cnt[edst[i]], 1);
        return;
    }
    const float* in; u16* out; int K, tb;
    if (b < 32)      { in = w1e; out = o1e; K = 512; tb = b; }
    else if (b < 48) { in = w2e; out = o2e; K = 256; tb = b - 32; }
    else if (b < 80) { in = w1g; out = o1g; K = 512; tb = b - 48; }
    else             { in = w2g; out = o2g; K = 256; tb = b - 80; }
    const int N = 256;
    const int ntn = N >> 6;               // 4
    const int tk = tb / ntn, tn = tb % ntn;
    const int k0 = tk << 6, n0 = tn << 6;
    #pragma unroll
    for (int i = 0; i < 4; ++i) {
        int flat = tid + 256 * i;
        int r = flat >> 4;
        int c = (flat & 15) << 2;
        *(float4*)&tile[r][c] = *(const float4*)(in + (size_t)(k0 + r) * N + n0 + c);
    }
    __syncthreads();
    #pragma unroll
    for (int i = 0; i < 2; ++i) {
        int flat = tid + 256 * i;
        int r = flat >> 3;
        int c = (flat & 7) << 3;
        uint4 o;
        o.x = pack2(f2bf(tile[c + 0][r]), f2bf(tile[c + 1][r]));
        o.y = pack2(f2bf(tile[c + 2][r]), f2bf(tile[c + 3][r]));
        o.z = pack2(f2bf(tile[c + 4][r]), f2bf(tile[c + 5][r]));
        o.w = pack2(f2bf(tile[c + 6][r]), f2bf(tile[c + 7][r]));
        *(uint4*)(out + (size_t)(n0 + r) * K + k0 + c) = o;
    }
}

// one block, 1024 threads; cnt may alias cursor (in-place read-then-write).
__global__ void scan_k(const int* cnt, int* row_start, int* cursor) {
    __shared__ int part[1024];
    const int t = threadIdx.x;
    const int chunk = (NG + 1023) / 1024;       // 98
    const int lo = t * chunk;
    const int hi = (lo + chunk < NG) ? lo + chunk : NG;
    int s = 0;
    for (int i = lo; i < hi; ++i) s += cnt[i];
    const int own = s;
    part[t] = s;
    __syncthreads();
    for (int off = 1; off < 1024; off <<= 1) {
        int v = (t >= off) ? part[t - off] : 0;
        __syncthreads();
        part[t] += v;
        __syncthreads();
    }
    int run = part[t] - own;                    // exclusive prefix
    for (int i = lo; i < hi; ++i) {
        int v = cnt[i];
        row_start[i] = run;
        cursor[i] = run;
        run += v;
    }
    if (t == 0) row_start[NG] = NE;
}

__global__ void scatter_k(const int* __restrict__ edst, int* cursor,
                          int* __restrict__ eid) {
    int i = blockIdx.x * blockDim.x + threadIdx.x;
    const int stride = gridDim.x * blockDim.x;
    for (; i < NE; i += stride) {
        int pos = atomicAdd(&cursor[edst[i]], 1);
        eid[pos] = i;
    }
}

// ---- mesh_part = mesh_x @ w1e[:256,:]  (f32 out, no bias) ----------------
__global__ __launch_bounds__(256, 2) void mp_k(
    const float* __restrict__ mesh_x, const u16* __restrict__ w1T,
    float* __restrict__ mesh_part)
{
    __shared__ u16 aC[64 * 32];
    __shared__ u16 bC[256 * 32];

    const int tid = threadIdx.x;
    const int r0 = blockIdx.x * 64;
    const int wv = tid >> 6;
    const int lane = tid & 63;
    const int m = lane & 15;
    const int q = lane >> 4;
    const int sr = tid >> 2;
    const int sc8 = (tid & 3) * 8;
    int srow = r0 + sr; if (srow >= NM) srow = NM - 1;

    f32x4 zero = {0.f, 0.f, 0.f, 0.f};
    f32x4 acc[4][4];
    #pragma unroll
    for (int i = 0; i < 4; ++i)
        #pragma unroll
        for (int j = 0; j < 4; ++j) acc[i][j] = zero;

    for (int kt = 0; kt < 8; ++kt) {
        const int kg = kt * 32;
        if (kt) __syncthreads();
        {
            const float* p = mesh_x + (size_t)srow * DD + kg + sc8;
            float4 v0 = *(const float4*)p;
            float4 v1 = *(const float4*)(p + 4);
            *(uint4*)&aC[sr * 32 + sc8] = pack8(v0, v1);
        }
        #pragma unroll
        for (int i = 0; i < 4; ++i) {
            int flat = tid + 256 * i;
            int n = flat >> 2;
            int c = (flat & 3) * 8;
            *(uint4*)&bC[n * 32 + c] = *(const uint4*)(w1T + (size_t)n * 512 + kg + c);
        }
        __syncthreads();
        bf16x8 af[4], bfr[4];
        #pragma unroll
        for (int et = 0; et < 4; ++et)
            af[et] = *(const bf16x8*)&aC[(et * 16 + m) * 32 + q * 8];
        #pragma unroll
        for (int ht = 0; ht < 4; ++ht)
            bfr[ht] = *(const bf16x8*)&bC[(wv * 64 + ht * 16 + m) * 32 + q * 8];
        #pragma unroll
        for (int ht = 0; ht < 4; ++ht)
            #pragma unroll
            for (int et = 0; et < 4; ++et)
                acc[ht][et] = __builtin_amdgcn_mfma_f32_16x16x32_bf16(
                    bfr[ht], af[et], acc[ht][et], 0, 0, 0);
    }

    #pragma unroll
    for (int nt = 0; nt < 4; ++nt) {
        const int nb = wv * 64 + nt * 16 + q * 4;
        #pragma unroll
        for (int et = 0; et < 4; ++et) {
            const int r = r0 + et * 16 + m;
            if (r < NM) {
                float4 o;
                o.x = acc[nt][et][0];
                o.y = acc[nt][et][1];
                o.z = acc[nt][et][2];
                o.w = acc[nt][et][3];
                *(float4*)(mesh_part + (size_t)r * HH + nb) = o;
            }
        }
    }
}

// ---------------- edge MLP + GEMM3 segment-sum aggregation ----------------
// r6 base + BK=64: each GEMM stages a 64-wide K-tile per barrier pair
// (4 exposures per GEMM instead of 8). PITCH 72 (144 B rows): keeps every
// uint4/bf16x8 LDS access 16B-aligned (pitch 68 = 136 B rows misaligns odd
// rows -> ds_*_b128 fault, r8 lesson); row shift 4 banks -> <=2-way conflict.
// GEMM3 one-pass hi/lo unchanged. LDS 81680 B -> 2 blocks/CU.
__global__ __launch_bounds__(256, 2) void edge_mlp_csr(
    const float* __restrict__ grid_x, const float* __restrict__ mesh_part,
    const int* __restrict__ esrc, const int* __restrict__ edst,
    const int* __restrict__ eid,
    const u16* __restrict__ w1T, const float* __restrict__ b1,
    const u16* __restrict__ w2T, const float* __restrict__ b2,
    float* __restrict__ agg)
{
    extern __shared__ char smem[];
    // main phase:
    u16* aC = (u16*)smem;                 // [64][72]                 9216 B
    u16* bC = aC + 64 * 72;               // [256][72]               36864 B (ends 46080)
    u16* hL = bC + 256 * 72;              // h1 [64][272]            34816 B (ends 80896)
    // GEMM3 overlays (aC/bC/hL dead by then):
    u16* hA = (u16*)smem;                 // h2hi [256][64] swz      32768 B
    u16* sS = (u16*)(smem + 32768);       // S    [64][64]  swz       8192 B
    u16* hB = (u16*)(smem + 40960);       // h2lo [256][64] swz      32768 B (ends 73728)
    // tail (never overlaid):
    int* ssrc = (int*)(smem + 80896);     // [64]
    int* sdst = ssrc + 64;                // [64]
    int* rowOfRank = sdst + 64;           // [64]
    int* miscL = rowOfRank + 64;          // [1] nD

    const int tid = threadIdx.x;
    const int e0 = blockIdx.x * 64;
    const int nT = (NE - e0 < 64) ? (NE - e0) : 64;

    const int wv = tid >> 6;
    const int lane = tid & 63;
    const int m = lane & 15;
    const int q = lane >> 4;
    const int sr = tid >> 2;              // staging row 0..63 (edge in tile)
    const int sc8 = (tid & 3) * 8;        // staging col (8 f32 per lane)

    int eS; { int ii = e0 + sr; eS = eid[(ii < NE) ? ii : NE - 1]; }
    const int rdst = edst[eS];
    if (tid < 64) {
        int ii = e0 + tid;
        int e = eid[(ii < NE) ? ii : NE - 1];
        ssrc[tid] = esrc[e];
        sdst[tid] = edst[e];
    }
    __syncthreads();                      // indices visible

    f32x4 zero = {0.f, 0.f, 0.f, 0.f};
    f32x4 acc[4][4];
    #pragma unroll
    for (int i = 0; i < 4; ++i)
        #pragma unroll
        for (int j = 0; j < 4; ++j) acc[i][j] = zero;

    // ---- GEMM1 (grid side): K = 256, BK = 64, 4 staging exposures ----
    for (int kt = 0; kt < 4; ++kt) {
        const int kg = kt * 64;
        if (kt) __syncthreads();
        {
            const float* p = grid_x + (size_t)rdst * DD + kg + sc8;
            float4 v0 = *(const float4*)p;
            float4 v1 = *(const float4*)(p + 4);
            float4 v2 = *(const float4*)(p + 32);
            float4 v3 = *(const float4*)(p + 36);
            *(uint4*)&aC[sr * 72 + sc8]      = pack8(v0, v1);
            *(uint4*)&aC[sr * 72 + 32 + sc8] = pack8(v2, v3);
        }
        #pragma unroll
        for (int i = 0; i < 8; ++i) {
            int flat = tid + 256 * i;
            int n = flat >> 3;
            int c = (flat & 7) * 8;
            *(uint4*)&bC[n * 72 + c] = *(const uint4*)(w1T + (size_t)n * 512 + 256 + kg + c);
        }
        __syncthreads();
        #pragma unroll
        for (int kk = 0; kk < 2; ++kk) {
            bf16x8 af[4], bfr[4];
            #pragma unroll
            for (int et = 0; et < 4; ++et)
                af[et] = *(const bf16x8*)&aC[(et * 16 + m) * 72 + kk * 32 + q * 8];
            #pragma unroll
            for (int ht = 0; ht < 4; ++ht)
                bfr[ht] = *(const bf16x8*)&bC[(wv * 64 + ht * 16 + m) * 72 + kk * 32 + q * 8];
            #pragma unroll
            for (int ht = 0; ht < 4; ++ht)
                #pragma unroll
                for (int et = 0; et < 4; ++et)
                    acc[ht][et] = __builtin_amdgcn_mfma_f32_16x16x32_bf16(
                        bfr[ht], af[et], acc[ht][et], 0, 0, 0);
        }
    }

    // ---- epilogue 1: h1 = relu(acc + mesh_part[src] + b1) -> hL bf16 ----
    #pragma unroll
    for (int ht = 0; ht < 4; ++ht) {
        const int hb = wv * 64 + ht * 16 + q * 4;
        const float4 bb = *(const float4*)(b1 + hb);
        #pragma unroll
        for (int et = 0; et < 4; ++et) {
            const int e = et * 16 + m;
            const float4 mp = *(const float4*)(mesh_part + (size_t)ssrc[e] * HH + hb);
            ushort4 o;
            o.x = f2bf(fmaxf(acc[ht][et][0] + mp.x + bb.x, 0.f));
            o.y = f2bf(fmaxf(acc[ht][et][1] + mp.y + bb.y, 0.f));
            o.z = f2bf(fmaxf(acc[ht][et][2] + mp.z + bb.z, 0.f));
            o.w = f2bf(fmaxf(acc[ht][et][3] + mp.w + bb.w, 0.f));
            *(ushort4*)&hL[e * 272 + hb] = o;
        }
    }
    #pragma unroll
    for (int i = 0; i < 4; ++i)
        #pragma unroll
        for (int j = 0; j < 4; ++j) acc[i][j] = zero;
    __syncthreads();                      // h1 visible; GEMM1 bC reads done

    // ---- GEMM2: K = 256, BK = 64, 4 staging exposures ----
    for (int kt = 0; kt < 4; ++kt) {
        const int kg = kt * 64;
        if (kt) __syncthreads();
        #pragma unroll
        for (int i = 0; i < 8; ++i) {
            int flat = tid + 256 * i;
            int n = flat >> 3;
            int c = (flat & 7) * 8;
            *(uint4*)&bC[n * 72 + c] = *(const uint4*)(w2T + (size_t)n * 256 + kg + c);
        }
        __syncthreads();
        #pragma unroll
        for (int kk = 0; kk < 2; ++kk) {
            bf16x8 af[4], bfr[4];
            #pragma unroll
            for (int et = 0; et < 4; ++et)
                af[et] = *(const bf16x8*)&hL[(et * 16 + m) * 272 + kg + kk * 32 + q * 8];
            #pragma unroll
            for (int ht = 0; ht < 4; ++ht)
                bfr[ht] = *(const bf16x8*)&bC[(wv * 64 + ht * 16 + m) * 72 + kk * 32 + q * 8];
            #pragma unroll
            for (int ht = 0; ht < 4; ++ht)
                #pragma unroll
                for (int et = 0; et < 4; ++et)
                    acc[ht][et] = __builtin_amdgcn_mfma_f32_16x16x32_bf16(
                        bfr[ht], af[et], acc[ht][et], 0, 0, 0);
        }
    }

    // ---- GEMM3 phase A: consume acc ONCE -> h2hi/h2lo LDS; zero S ----
    __syncthreads();                      // all GEMM2 reads of bC/hL done
    #pragma unroll
    for (int nt = 0; nt < 4; ++nt) {
        const int hb = wv * 64 + nt * 16 + q * 4;
        const float4 bb = *(const float4*)(b2 + hb);
        #pragma unroll
        for (int et = 0; et < 4; ++et) {
            const int el = et * 16 + m;
            #pragma unroll
            for (int j = 0; j < 4; ++j) {
                float x = acc[nt][et][j] +
                          ((j == 0) ? bb.x : (j == 1) ? bb.y : (j == 2) ? bb.z : bb.w);
                u16 hi = f2bf(x);
                union { unsigned int i; float f; } hf2;
                hf2.i = ((unsigned int)hi) << 16;
                u16 lo = f2bf(x - hf2.f);
                const int row = hb + j;
                const int col = (el & 7) | (((el >> 3) ^ (row & 7)) << 3);
                hA[row * 64 + col] = hi;
                hB[row * 64 + col] = lo;
            }
        }
    }
    for (int i = tid; i < (64 * 64) / 8; i += 256)
        ((uint4*)sS)[i] = make_uint4(0, 0, 0, 0);
    __syncthreads();

    // ---- rank ballot -> rowOfRank, one-hot S (swizzled) ----
    if (tid < 64) {
        int d = sdst[tid];
        bool flag = (tid > 0) && (tid < nT) && (d != sdst[tid - 1]);
        unsigned long long mask = __ballot(flag);
        int rk = (int)__popcll(mask & ((2ull << tid) - 1ull));
        if (tid < nT) {
            rowOfRank[rk] = d;
            const int scol = (tid & 7) | (((tid >> 3) ^ (rk & 7)) << 3);
            sS[rk * 64 + scol] = (u16)0x3F80;         // bf16 1.0
        }
        if (tid == 0) miscL[0] = (int)__popcll(mask) + 1;
    }
    __syncthreads();

    // ---- GEMM3 phase B: acc3 = (h2hi + h2lo) x S, 4 MFMA steps ----
    f32x4 acc3[4][4];
    #pragma unroll
    for (int i = 0; i < 4; ++i)
        #pragma unroll
        for (int j = 0; j < 4; ++j) acc3[i][j] = zero;

    #pragma unroll
    for (int ph = 0; ph < 2; ++ph) {
        const u16* hsrc = ph ? hB : hA;
        #pragma unroll
        for (int ks = 0; ks < 2; ++ks) {
            bf16x8 hf[4], sf[4];
            #pragma unroll
            for (int ht = 0; ht < 4; ++ht) {
                const int r = wv * 64 + ht * 16 + m;
                const int cs = ((ks * 4 + q) ^ (r & 7)) * 8;
                hf[ht] = *(const bf16x8*)&hsrc[r * 64 + cs];
            }
            #pragma unroll
            for (int rt = 0; rt < 4; ++rt) {
                const int rs = rt * 16 + m;
                const int cs = ((ks * 4 + q) ^ (rs & 7)) * 8;
                sf[rt] = *(const bf16x8*)&sS[rs * 64 + cs];
            }
            #pragma unroll
            for (int ht = 0; ht < 4; ++ht)
                #pragma unroll
                for (int rt = 0; rt < 4; ++rt)
                    acc3[ht][rt] = __builtin_amdgcn_mfma_f32_16x16x32_bf16(
                        hf[ht], sf[rt], acc3[ht][rt], 0, 0, 0);
        }
    }

    // ---- epilogue 3: store per-rank partial sums ----
    const int nD = miscL[0];
    #pragma unroll
    for (int ht = 0; ht < 4; ++ht) {
        const int h0 = wv * 64 + ht * 16 + q * 4;
        #pragma unroll
        for (int rt = 0; rt < 4; ++rt) {
            const int r = rt * 16 + m;
            if (r < nD) {
                float* p = agg + (size_t)rowOfRank[r] * HH + h0;
                if (r == 0 || r == nD - 1) {      // may straddle block boundary
                    unsafeAtomicAdd(p + 0, acc3[ht][rt][0]);
                    unsafeAtomicAdd(p + 1, acc3[ht][rt][1]);
                    unsafeAtomicAdd(p + 2, acc3[ht][rt][2]);
                    unsafeAtomicAdd(p + 3, acc3[ht][rt][3]);
                } else {                          // exclusively owned row
                    float4 o;
                    o.x = acc3[ht][rt][0];
                    o.y = acc3[ht][rt][1];
                    o.z = acc3[ht][rt][2];
                    o.w = acc3[ht][rt][3];
                    *(float4*)p = o;
                }
            }
        }
    }
}

// ---------------- grid MLP + residual (r6 structure + BK=64, pitch 72) ------
// agg is f32 [NG][HH] living in d_out; block-local read-then-write.
// NOTE: agg and out alias — no __restrict__ on them.
__global__ __launch_bounds__(256, 2) void grid_mlp(
    const float* __restrict__ grid_x, const float* agg,
    const u16* __restrict__ w1T, const float* __restrict__ b1,
    const u16* __restrict__ w2T, const float* __restrict__ b2,
    float* out)
{
    __shared__ u16 aC[64 * 72];
    __shared__ u16 bC[256 * 72];
    __shared__ u16 hL[64 * 272];

    const int tid = threadIdx.x;
    const int r0 = blockIdx.x * 64;
    const int wv = tid >> 6;
    const int lane = tid & 63;
    const int m = lane & 15;
    const int q = lane >> 4;
    const int sr = tid >> 2;
    const int sc8 = (tid & 3) * 8;
    int srow = r0 + sr; if (srow >= NG) srow = NG - 1;  // clamp stays inside block

    f32x4 zero = {0.f, 0.f, 0.f, 0.f};
    f32x4 acc[4][4];
    #pragma unroll
    for (int i = 0; i < 4; ++i)
        #pragma unroll
        for (int j = 0; j < 4; ++j) acc[i][j] = zero;

    // ---- GEMM1: K = 512 (concat grid_x | agg), BK = 64, 8 exposures ----
    for (int kt = 0; kt < 8; ++kt) {
        const int kg = kt * 64;
        if (kt) __syncthreads();
        {
            const int col = kg + sc8;
            const float* p = (col < DD)
                ? (grid_x + (size_t)srow * DD + col)
                : (agg + (size_t)srow * HH + (col - DD));
            float4 v0 = *(const float4*)p;
            float4 v1 = *(const float4*)(p + 4);
            const int col2 = col + 32;
            const float* p2 = (col2 < DD)
                ? (grid_x + (size_t)srow * DD + col2)
                : (agg + (size_t)srow * HH + (col2 - DD));
            float4 v2 = *(const float4*)p2;
            float4 v3 = *(const float4*)(p2 + 4);
            *(uint4*)&aC[sr * 72 + sc8]      = pack8(v0, v1);
            *(uint4*)&aC[sr * 72 + 32 + sc8] = pack8(v2, v3);
        }
        #pragma unroll
        for (int i = 0; i < 8; ++i) {
            int flat = tid + 256 * i;
            int n = flat >> 3;
            int c = (flat & 7) * 8;
            *(uint4*)&bC[n * 72 + c] = *(const uint4*)(w1T + (size_t)n * 512 + kg + c);
        }
        __syncthreads();
        #pragma unroll
        for (int kk = 0; kk < 2; ++kk) {
            bf16x8 af[4], bfr[4];
            #pragma unroll
            for (int et = 0; et < 4; ++et)
                af[et] = *(const bf16x8*)&aC[(et * 16 + m) * 72 + kk * 32 + q * 8];
            #pragma unroll
            for (int ht = 0; ht < 4; ++ht)
                bfr[ht] = *(const bf16x8*)&bC[(wv * 64 + ht * 16 + m) * 72 + kk * 32 + q * 8];
            #pragma unroll
            for (int ht = 0; ht < 4; ++ht)
                #pragma unroll
                for (int et = 0; et < 4; ++et)
                    acc[ht][et] = __builtin_amdgcn_mfma_f32_16x16x32_bf16(
                        bfr[ht], af[et], acc[ht][et], 0, 0, 0);
        }
    }

    // ---- epilogue 1: bias + relu -> hL ----
    #pragma unroll
    for (int ht = 0; ht < 4; ++ht) {
        const int hb = wv * 64 + ht * 16 + q * 4;
        const float4 bb = *(const float4*)(b1 + hb);
        #pragma unroll
        for (int et = 0; et < 4; ++et) {
            const int e = et * 16 + m;
            ushort4 o;
            o.x = f2bf(fmaxf(acc[ht][et][0] + bb.x, 0.f));
            o.y = f2bf(fmaxf(acc[ht][et][1] + bb.y, 0.f));
            o.z = f2bf(fmaxf(acc[ht][et][2] + bb.z, 0.f));
            o.w = f2bf(fmaxf(acc[ht][et][3] + bb.w, 0.f));
            *(ushort4*)&hL[e * 272 + hb] = o;
        }
    }
    #pragma unroll
    for (int i = 0; i < 4; ++i)
        #pragma unroll
        for (int j = 0; j < 4; ++j) acc[i][j] = zero;
    __syncthreads();                      // hL visible; GEMM1 bC reads done

    // ---- GEMM2: K = 256, BK = 64, 4 exposures ----
    for (int kt = 0; kt < 4; ++kt) {
        const int kg = kt * 64;
        if (kt) __syncthreads();
        #pragma unroll
        for (int i = 0; i < 8; ++i) {
            int flat = tid + 256 * i;
            int n = flat >> 3;
            int c = (flat & 7) * 8;
            *(uint4*)&bC[n * 72 + c] = *(const uint4*)(w2T + (size_t)n * 256 + kg + c);
        }
        __syncthreads();
        #pragma unroll
        for (int kk = 0; kk < 2; ++kk) {
            bf16x8 af[4], bfr[4];
            #pragma unroll
            for (int et = 0; et < 4; ++et)
                af[et] = *(const bf16x8*)&hL[(et * 16 + m) * 272 + kg + kk * 32 + q * 8];
            #pragma unroll
            for (int ht = 0; ht < 4; ++ht)
                bfr[ht] = *(const bf16x8*)&bC[(wv * 64 + ht * 16 + m) * 72 + kk * 32 + q * 8];
            #pragma unroll
            for (int ht = 0; ht < 4; ++ht)
                #pragma unroll
                for (int et = 0; et < 4; ++et)
                    acc[ht][et] = __builtin_amdgcn_mfma_f32_16x16x32_bf16(
                        bfr[ht], af[et], acc[ht][et], 0, 0, 0);
        }
    }

    // ---- epilogue: + b2 + residual grid_x, store f32 (overwrites agg rows)
    #pragma unroll
    for (int nt = 0; nt < 4; ++nt) {
        const int nb = wv * 64 + nt * 16 + q * 4;
        const float4 bb = *(const float4*)(b2 + nb);
        #pragma unroll
        for (int et = 0; et < 4; ++et) {
            const int r = r0 + et * 16 + m;
            if (r < NG) {
                const float4 g = *(const float4*)(grid_x + (size_t)r * DD + nb);
                float4 o;
                o.x = acc[nt][et][0] + bb.x + g.x;
                o.y = acc[nt][et][1] + bb.y + g.y;
                o.z = acc[nt][et][2] + bb.z + g.z;
                o.w = acc[nt][et][3] + bb.w + g.w;
                *(float4*)(out + (size_t)r * DD + nb) = o;
            }
        }
    }
}

extern "C" void kernel_launch(void* const* d_in, const int* in_sizes, int n_in,
                              void* d_out, int out_size, void* d_ws, size_t ws_size,
                              hipStream_t stream)
{
    const float* mesh_x = (const float*)d_in[0];
    const float* grid_x = (const float*)d_in[1];
    const int* esrc     = (const int*)d_in[2];
    const int* edst     = (const int*)d_in[3];
    const float* w1e    = (const float*)d_in[4];
    const float* b1e    = (const float*)d_in[5];
    const float* w2e    = (const float*)d_in[6];
    const float* b2e    = (const float*)d_in[7];
    const float* w1g    = (const float*)d_in[8];
    const float* b1g    = (const float*)d_in[9];
    const float* w2g    = (const float*)d_in[10];
    const float* b2g    = (const float*)d_in[11];
    float* out = (float*)d_out;

    // d_ws layout: 4 transposed bf16 weights (768 KB) + CSR (2.0 MB)
    //              + mesh_part f32 [NM][HH] (10.24 MB)  => ~13 MB total
    u16* w1eT = (u16*)d_ws;
    u16* w2eT = w1eT + 512 * 256;
    u16* w1gT = w2eT + 256 * 256;
    u16* w2gT = w1gT + 512 * 256;
    int* row_start = (int*)(w2gT + 256 * 256);   // [NG+4] (pad keeps 16B align)
    int* cursor    = row_start + NG + 4;         // [NG]
    int* eid       = cursor + NG;                // [NE]
    float* mesh_part = (float*)(eid + NE);       // [NM][HH] f32

    // agg f32 [NG][HH] lives in d_out; zero it (atomic targets + empty rows)
    hipMemsetAsync(d_out, 0, (size_t)NG * HH * sizeof(float), stream);
    hipMemsetAsync(cursor, 0, (size_t)NG * sizeof(int), stream);

    // fused: 4 weight transposes (96 blocks) + dst histogram (256 blocks)
    transpose_hist<<<96 + 256, 256, 0, stream>>>(
        w1e, w2e, w1g, w2g, w1eT, w2eT, w1gT, w2gT, edst, cursor);

    scan_k<<<1, 1024, 0, stream>>>(cursor, row_start, cursor);
    scatter_k<<<256, 256, 0, stream>>>(edst, cursor, eid);

    // mesh_part = mesh_x @ w1e_top  (f32)
    mp_k<<<(NM + 63) / 64, 256, 0, stream>>>(mesh_x, w1eT, mesh_part);

    // edge MLP + GEMM3 aggregation (boundary-only atomics)
    const int smem_bytes = 80896 + 784;   // 81680 B -> 2 blocks/CU
    hipFuncSetAttribute(reinterpret_cast<const void*>(edge_mlp_csr),
                        hipFuncAttributeMaxDynamicSharedMemorySize, smem_bytes);
    edge_mlp_csr<<<NB, 256, smem_bytes, stream>>>(
        grid_x, mesh_part, esrc, edst, eid,
        w1eT, b1e, w2eT, b2e, (float*)d_out);

    grid_mlp<<<(NG + 63) / 64, 256, 0, stream>>>(
        grid_x, (const float*)d_out, w1gT, b1g, w2gT, b2g, out);
}